// Round 5
// baseline (47392.694 us; speedup 1.0000x reference)
//
#include <hip/hip_runtime.h>
#include <math.h>

#define S_LEN 2048
#define FIN 9
#define NOUT 8
#define LBK 3
#define DD 11
#define K1 33
#define H2 512
#define UU 256
#define NSTEP 2044
#define MR 8
#define GRID 128
#define LN_EPS 1e-3f

typedef __attribute__((ext_vector_type(8))) short short8;
typedef __attribute__((ext_vector_type(4))) float f32x4;
typedef __attribute__((ext_vector_type(4))) unsigned short us4;

// ---- packed B-fragment pool (bf16): tile (nt,kt): 64 lanes x 8 bf16,
// elem = B[k][n], k = kt*32 + (lane>>4)*8 + j, n = nt*16 + (lane&15)
#define F_EW1 (32 * 2 * 512)
#define F_EW2 (16 * 16 * 512)
#define F_UW  (16 * 8 * 512)
#define F_DW1 (32 * 8 * 512)
#define F_DW2 (1 * 16 * 512)
#define O_EW1 0
#define O_EW2 (O_EW1 + F_EW1)
#define O_UW  (O_EW2 + F_EW2)
#define O_DW1 (O_UW + F_UW)
#define O_DW2 (O_DW1 + F_DW1)
#define W_TOT (O_DW2 + F_DW2)   // 368640 elems = 737280 B

__device__ __forceinline__ unsigned short f2bf(float f) {
    unsigned u = __float_as_uint(f);
    u = (u + 0x7fffu + ((u >> 16) & 1u)) >> 16;
    return (unsigned short)u;
}
__device__ __forceinline__ float bf2f(unsigned short u) {
    return __uint_as_float(((unsigned)u) << 16);
}
__device__ __forceinline__ float ftanh(float x) {
    float ax = fabsf(x);
    float e = __expf(-2.0f * ax);
    float r = __fdividef(1.0f - e, 1.0f + e);
    return copysignf(r, x);
}

extern "C" __global__ void convw(const float* __restrict__ ew1, const float* __restrict__ ew2,
                                 const float* __restrict__ uw,  const float* __restrict__ dw1,
                                 const float* __restrict__ dw2, unsigned short* __restrict__ o)
{
    int i = blockIdx.x * blockDim.x + threadIdx.x;
    if (i >= W_TOT) return;
    int p, KT, K, N; const float* W;
    if (i < O_EW2)      { p = i - O_EW1; KT = 2;  K = 33;  N = 512; W = ew1; }
    else if (i < O_UW)  { p = i - O_EW2; KT = 16; K = 512; N = 256; W = ew2; }
    else if (i < O_DW1) { p = i - O_UW;  KT = 8;  K = 256; N = 256; W = uw;  }
    else if (i < O_DW2) { p = i - O_DW1; KT = 8;  K = 256; N = 512; W = dw1; }
    else                { p = i - O_DW2; KT = 16; K = 512; N = 8;   W = dw2; }
    int frag = p >> 9, rem = p & 511;
    int ln = rem >> 3, j = rem & 7;
    int nt = frag / KT, kt = frag % KT;
    int k = kt * 32 + (ln >> 4) * 8 + j;
    int n = nt * 16 + (ln & 15);
    float v = 0.f;
    if (k < K && n < N) v = W[k * N + n];
    o[i] = f2bf(v);
}

extern "C" __global__ void __launch_bounds__(1024)
solver(const float* __restrict__ inputs,
       const unsigned short* __restrict__ pool,
       const float* __restrict__ g1v, const float* __restrict__ b1v,
       const float* __restrict__ eb1, const float* __restrict__ eb2,
       const float* __restrict__ ub,  const float* __restrict__ g2v,
       const float* __restrict__ b2v, const float* __restrict__ bww,
       const float* __restrict__ dw1, const float* __restrict__ db1,
       const float* __restrict__ db2, const int* __restrict__ fixv,
       float* __restrict__ out)
{
    __shared__ unsigned short xs[MR * 72];     // LN1 out (33 used, zeros to 64)
    __shared__ unsigned short h1[MR * 520];    // tanh(enc1)
    __shared__ unsigned short hsb[MR * 264];   // enc2 out
    __shared__ __align__(16) float uu[MR * 260];   // upd out fp32
    __shared__ unsigned short cmb[MR * 264];   // LN2 out bf16
    __shared__ unsigned short gsb[MR * 520];   // tanh(dec1)
    __shared__ float red2[16][MR][9];
    __shared__ float ects[MR];
    __shared__ float ring[3][MR][NOUT];
    __shared__ float s_eb1[512], s_eb2[256], s_ub[256], s_db1[512], s_db2[8];
    __shared__ __align__(16) float s_bw[256];
    __shared__ __align__(16) float s_g2[256];
    __shared__ __align__(16) float s_b2[256];
    __shared__ float s_w257[512];
    __shared__ float s_g1[DD], s_b1[DD];

    const int tid = threadIdx.x;
    const int lane = tid & 63;
    const int wv = tid >> 6;      // 0..15
    const int q = lane >> 4;      // 0..3
    const int lc = lane & 15;     // tile col / output col
    const int lr = lc & 7;        // A-row (rows 8..15 duplicate 0..7)
    const int b0 = blockIdx.x * MR;
    const int fx0 = fixv[0], fx1 = fixv[1];

    // ---- preamble: params, zero xs, ring init ----
    for (int z = tid; z < MR * 72; z += 1024) xs[z] = 0;
    for (int z = tid; z < 512; z += 1024) { s_eb1[z] = eb1[z]; s_db1[z] = db1[z]; s_w257[z] = dw1[256 * 512 + z]; }
    for (int z = tid; z < 256; z += 1024) { s_eb2[z] = eb2[z]; s_ub[z] = ub[z]; s_bw[z] = bww[z]; s_g2[z] = g2v[z]; s_b2[z] = b2v[z]; }
    if (tid < 8) s_db2[tid] = db2[tid];
    if (tid >= 16 && tid < 16 + DD) { s_g1[tid - 16] = g1v[tid - 16]; s_b1[tid - 16] = b1v[tid - 16]; }
    if (tid < MR * LBK * NOUT) {
        int r = tid / (LBK * NOUT);
        int rem = tid % (LBK * NOUT);
        int p = rem / NOUT, f = rem % NOUT;
        ring[p][r][f] = inputs[((size_t)(b0 + r) * S_LEN + p) * FIN + 1 + f];
    }

    // ---- pinned fragments (step-invariant) ----
    short8 fD[8], fG;
    #pragma unroll
    for (int kt = 0; kt < 8; ++kt)
        fD[kt] = *(const short8*)&pool[O_UW + (((wv << 3) + kt) << 9) + (lane << 3)];
    fG = *(const short8*)&pool[O_DW2 + (wv << 9) + (lane << 3)];

    // streamed fragments
    short8 fB[4], fC[16], fF[16];
    #pragma unroll
    for (int half = 0; half < 2; ++half)
        #pragma unroll
        for (int kt = 0; kt < 2; ++kt)
            fB[half * 2 + kt] = *(const short8*)&pool[O_EW1 + ((((2 * wv + half) << 1) + kt) << 9) + (lane << 3)];

    __syncthreads();

    // ---- stage A for t=0 ----
    if (tid < MR * LBK) {
        int r = tid / LBK, p = tid % LBK;
        int b = b0 + r;
        int tt = p;
        float ld = inputs[((size_t)b * S_LEN + tt) * FIN];
        float df = (tt > 0) ? ld - inputs[((size_t)b * S_LEN + tt - 1) * FIN] : 0.f;
        float v[DD];
        v[0] = ld; v[1] = ld; v[2] = df;
        #pragma unroll
        for (int f = 0; f < NOUT; ++f) v[3 + f] = ring[tt % 3][r][f];
        float m = 0.f;
        #pragma unroll
        for (int j = 0; j < DD; ++j) m += v[j];
        m *= (1.0f / DD);
        float var = 0.f;
        #pragma unroll
        for (int j = 0; j < DD; ++j) { float d = v[j] - m; var += d * d; }
        var *= (1.0f / DD);
        float rs = rsqrtf(var + LN_EPS);
        #pragma unroll
        for (int j = 0; j < DD; ++j)
            xs[r * 72 + p * DD + j] = f2bf((v[j] - m) * rs * s_g1[j] + s_b1[j]);
    }
    __syncthreads();

    for (int t = 0; t < NSTEP; ++t) {
        // ==== stage B: h1 = tanh(x @ ew1 + eb1), uses fB; prefetch fC[0..7] ====
        {
            #pragma unroll
            for (int j = 0; j < 8; ++j)
                fC[j] = *(const short8*)&pool[O_EW2 + (((wv << 4) + j) << 9) + (lane << 3)];
            #pragma unroll
            for (int half = 0; half < 2; ++half) {
                int nt = 2 * wv + half;
                float bias = s_eb1[nt * 16 + lc];
                f32x4 acc = {bias, bias, bias, bias};
                #pragma unroll
                for (int kt = 0; kt < 2; ++kt) {
                    short8 af = *(const short8*)&xs[lr * 72 + kt * 32 + q * 8];
                    acc = __builtin_amdgcn_mfma_f32_16x16x32_bf16(af, fB[half * 2 + kt], acc, 0, 0, 0);
                }
                if (q < 2) {
                    int col = nt * 16 + lc;
                    #pragma unroll
                    for (int r = 0; r < 4; ++r)
                        h1[(q * 4 + r) * 520 + col] = f2bf(ftanh(acc[r]));
                }
            }
        }
        __syncthreads();

        // ==== stage C: h = h1 @ ew2 + eb2; prefetch fC[8..15] (used late in stage) ====
        {
            #pragma unroll
            for (int j = 8; j < 16; ++j)
                fC[j] = *(const short8*)&pool[O_EW2 + (((wv << 4) + j) << 9) + (lane << 3)];
            float bias = s_eb2[wv * 16 + lc];
            f32x4 acc = {bias, bias, bias, bias};
            #pragma unroll
            for (int kt = 0; kt < 16; ++kt) {
                short8 af = *(const short8*)&h1[lr * 520 + kt * 32 + q * 8];
                acc = __builtin_amdgcn_mfma_f32_16x16x32_bf16(af, fC[kt], acc, 0, 0, 0);
            }
            if (q < 2) {
                int col = wv * 16 + lc;
                #pragma unroll
                for (int r = 0; r < 4; ++r)
                    hsb[(q * 4 + r) * 264 + col] = f2bf(acc[r]);
            }
        }
        __syncthreads();

        // ==== stage D: u = h @ uw + ub (pinned fD); prefetch fF[0..7] ====
        {
            #pragma unroll
            for (int j = 0; j < 8; ++j)
                fF[j] = *(const short8*)&pool[O_DW1 + ((((2 * wv) << 3) + j) << 9) + (lane << 3)];
            float bias = s_ub[wv * 16 + lc];
            f32x4 acc = {bias, bias, bias, bias};
            #pragma unroll
            for (int kt = 0; kt < 8; ++kt) {
                short8 af = *(const short8*)&hsb[lr * 264 + kt * 32 + q * 8];
                acc = __builtin_amdgcn_mfma_f32_16x16x32_bf16(af, fD[kt], acc, 0, 0, 0);
            }
            if (q < 2) {
                int col = wv * 16 + lc;
                #pragma unroll
                for (int r = 0; r < 4; ++r)
                    uu[(q * 4 + r) * 260 + col] = acc[r];
            }
        }
        __syncthreads();

        // ==== LN2 stats + cmb (waves 0..7, row = wv); prefetch fF[8..15] ====
        {
            #pragma unroll
            for (int j = 0; j < 8; ++j)
                fF[8 + j] = *(const short8*)&pool[O_DW1 + ((((2 * wv + 1) << 3) + j) << 9) + (lane << 3)];
            if (wv < 8) {
                const int r = wv;
                float4 u4 = *(const float4*)&uu[r * 260 + lane * 4];
                us4 h4 = *(const us4*)&hsb[r * 264 + lane * 4];
                float4 bw4 = *(const float4*)&s_bw[lane * 4];
                float s0 = u4.x + u4.y + u4.z + u4.w;
                float s1 = u4.x * u4.x + u4.y * u4.y + u4.z * u4.z + u4.w * u4.w;
                float s2 = bf2f(h4[0]) * bw4.x + bf2f(h4[1]) * bw4.y + bf2f(h4[2]) * bw4.z + bf2f(h4[3]) * bw4.w;
                #pragma unroll
                for (int mk = 1; mk < 64; mk <<= 1) {
                    s0 += __shfl_xor(s0, mk);
                    s1 += __shfl_xor(s1, mk);
                    s2 += __shfl_xor(s2, mk);
                }
                float mean = s0 * (1.0f / UU);
                float var = s1 * (1.0f / UU) - mean * mean;
                float rstd = rsqrtf(var + LN_EPS);
                if (lane == 0) ects[r] = s2;
                float4 g4 = *(const float4*)&s_g2[lane * 4];
                float4 bb4 = *(const float4*)&s_b2[lane * 4];
                us4 o;
                o[0] = f2bf((u4.x - mean) * rstd * g4.x + bb4.x);
                o[1] = f2bf((u4.y - mean) * rstd * g4.y + bb4.y);
                o[2] = f2bf((u4.z - mean) * rstd * g4.z + bb4.z);
                o[3] = f2bf((u4.w - mean) * rstd * g4.w + bb4.w);
                *(us4*)&cmb[r * 264 + lane * 4] = o;
            }
        }
        __syncthreads();

        // ==== stage F: g = tanh(comb @ dw1 + ect*w257 + db1) then fused
        // ==== stage G: y-partials = g @ dw2 (pinned fG; same-wave gsb reuse) ====
        {
            #pragma unroll
            for (int half = 0; half < 2; ++half) {
                int nt = 2 * wv + half;
                float bias = s_db1[nt * 16 + lc];
                f32x4 acc = {bias, bias, bias, bias};
                #pragma unroll
                for (int kt = 0; kt < 8; ++kt) {
                    short8 af = *(const short8*)&cmb[lr * 264 + kt * 32 + q * 8];
                    acc = __builtin_amdgcn_mfma_f32_16x16x32_bf16(af, fF[half * 8 + kt], acc, 0, 0, 0);
                }
                int col = nt * 16 + lc;
                float wc = s_w257[col];
                float e = ects[(q * 4 + 0) & 7];  // rows in this q-group share... no: per-r below
                (void)e;
                if (q < 2) {
                    #pragma unroll
                    for (int r = 0; r < 4; ++r) {
                        int row = q * 4 + r;
                        gsb[row * 520 + col] = f2bf(ftanh(acc[r] + ects[row] * wc));
                    }
                }
            }
            // G: wave wv handles kt=wv; A-data = gsb cols [32wv,32wv+32) written above by this wave
            f32x4 acc = {0.f, 0.f, 0.f, 0.f};
            {
                short8 af = *(const short8*)&gsb[lr * 520 + wv * 32 + q * 8];
                acc = __builtin_amdgcn_mfma_f32_16x16x32_bf16(af, fG, acc, 0, 0, 0);
            }
            if (q < 2 && lc < 8) {
                #pragma unroll
                for (int r = 0; r < 4; ++r)
                    red2[wv][q * 4 + r][lc] = acc[r];
            }
        }
        __syncthreads();

        // ==== finalize + stage A(t+1) (wave 0); all waves: reload fB ====
        {
            #pragma unroll
            for (int half = 0; half < 2; ++half)
                #pragma unroll
                for (int kt = 0; kt < 2; ++kt)
                    fB[half * 2 + kt] = *(const short8*)&pool[O_EW1 + ((((2 * wv + half) << 1) + kt) << 9) + (lane << 3)];
            if (wv == 0) {
                int r = lane >> 3, f = lane & 7;
                int b = b0 + r;
                float y = s_db2[f];
                #pragma unroll
                for (int w = 0; w < 16; ++w) y += red2[w][r][f];
                if (f == fx0) y = inputs[((size_t)b * S_LEN + t + 4) * FIN + 1 + fx0];
                if (f == fx1) y = inputs[((size_t)b * S_LEN + t + 4) * FIN + 1 + fx1];
                out[((size_t)(f * 1024 + b)) * NSTEP + t] = y;
                ring[t % 3][r][f] = y;
                // stage A for step t+1 (same wave: ring writes above are ordered before these reads)
                if (lane < MR * LBK) {
                    int ar = lane / LBK, p = lane % LBK;
                    int ab = b0 + ar;
                    int tt = t + 1 + p;
                    float ld = inputs[((size_t)ab * S_LEN + tt) * FIN];
                    float df = ld - inputs[((size_t)ab * S_LEN + tt - 1) * FIN];
                    float v[DD];
                    v[0] = ld; v[1] = ld; v[2] = df;
                    #pragma unroll
                    for (int ff = 0; ff < NOUT; ++ff) v[3 + ff] = ring[tt % 3][ar][ff];
                    float m = 0.f;
                    #pragma unroll
                    for (int j = 0; j < DD; ++j) m += v[j];
                    m *= (1.0f / DD);
                    float var = 0.f;
                    #pragma unroll
                    for (int j = 0; j < DD; ++j) { float d = v[j] - m; var += d * d; }
                    var *= (1.0f / DD);
                    float rs = rsqrtf(var + LN_EPS);
                    #pragma unroll
                    for (int j = 0; j < DD; ++j)
                        xs[ar * 72 + p * DD + j] = f2bf((v[j] - m) * rs * s_g1[j] + s_b1[j]);
                }
            }
        }
        __syncthreads();
    }
}

// ================= fallback (fp32 VALU, R3-proven) =================
#define MROW 4
#define NTF 1024
__global__ __launch_bounds__(NTF)
void solver_fb(const float* __restrict__ inputs,
               const float* __restrict__ g1v, const float* __restrict__ b1v,
               const float* __restrict__ ew1, const float* __restrict__ eb1,
               const float* __restrict__ ew2, const float* __restrict__ eb2,
               const float* __restrict__ uw,  const float* __restrict__ ub,
               const float* __restrict__ g2v, const float* __restrict__ b2v,
               const float* __restrict__ bww,
               const float* __restrict__ dw1, const float* __restrict__ db1,
               const float* __restrict__ dw2, const float* __restrict__ db2,
               const int* __restrict__ fixv,
               float* __restrict__ out)
{
    __shared__ float x33[MROW][K1];
    __shared__ float h1s[MROW * H2];
    __shared__ float hs[MROW * UU];
    __shared__ float combs[MROW][UU + 1];
    __shared__ float gs[MROW * H2];
    __shared__ float win[MROW][LBK][NOUT];
    __shared__ float redf[8192];
    __shared__ float red2[32][32];
    __shared__ float wred[16][3];
    __shared__ float rowstat[MROW][3];
    __shared__ float ynew[MROW][NOUT];
    float2* redf2 = reinterpret_cast<float2*>(redf);
    const int tid = threadIdx.x;
    const int b0 = blockIdx.x * MROW;
    const int fx0 = fixv[0], fx1 = fixv[1];
    if (tid < MROW * LBK * NOUT) {
        int r = tid / (LBK * NOUT);
        int rem = tid % (LBK * NOUT);
        int p = rem / NOUT, f = rem % NOUT;
        win[r][p][f] = inputs[((size_t)(b0 + r) * S_LEN + p) * FIN + 1 + f];
    }
    __syncthreads();
    for (int t = 0; t < NSTEP; ++t) {
        const int i = t + LBK;
        if (tid < MROW * LBK) {
            int r = tid / LBK, p = tid % LBK;
            int b = b0 + r;
            int tt = i - LBK + p;
            float ld = inputs[((size_t)b * S_LEN + tt) * FIN];
            float df = (tt > 0) ? ld - inputs[((size_t)b * S_LEN + tt - 1) * FIN] : 0.f;
            float v[DD];
            v[0] = ld; v[1] = ld; v[2] = df;
            #pragma unroll
            for (int f = 0; f < NOUT; ++f) v[3 + f] = win[r][p][f];
            float m = 0.f;
            #pragma unroll
            for (int j = 0; j < DD; ++j) m += v[j];
            m *= (1.0f / DD);
            float var = 0.f;
            #pragma unroll
            for (int j = 0; j < DD; ++j) { float d = v[j] - m; var += d * d; }
            var *= (1.0f / DD);
            float rs = rsqrtf(var + LN_EPS);
            #pragma unroll
            for (int j = 0; j < DD; ++j)
                x33[r][p * DD + j] = (v[j] - m) * rs * g1v[j] + b1v[j];
        }
        __syncthreads();
        {
            int cc = tid & 255, c0 = cc * 2;
            int ks = tid >> 8;
            int kbeg = ks * 8;
            int kend = (ks == 3) ? K1 : kbeg + 8;
            float2 acc[MROW];
            #pragma unroll
            for (int r = 0; r < MROW; ++r) acc[r] = make_float2(0.f, 0.f);
            for (int k = kbeg; k < kend; ++k) {
                float2 w = *reinterpret_cast<const float2*>(ew1 + (size_t)k * H2 + c0);
                #pragma unroll
                for (int r = 0; r < MROW; ++r) {
                    float xv = x33[r][k];
                    acc[r].x += xv * w.x; acc[r].y += xv * w.y;
                }
            }
            #pragma unroll
            for (int r = 0; r < MROW; ++r) redf2[ks * 1024 + r * 256 + cc] = acc[r];
        }
        __syncthreads();
        {
            #pragma unroll
            for (int jj = 0; jj < 2; ++jj) {
                int o = tid + jj * 1024;
                float v = redf[o] + redf[2048 + o] + redf[4096 + o] + redf[6144 + o] + eb1[o & 511];
                h1s[o] = tanhf(v);
            }
        }
        __syncthreads();
        {
            int cc = tid & 127, c0 = cc * 2;
            int ks = tid >> 7;
            int kbeg = ks * 64;
            float2 acc[MROW];
            #pragma unroll
            for (int r = 0; r < MROW; ++r) acc[r] = make_float2(0.f, 0.f);
            #pragma unroll 8
            for (int k = kbeg; k < kbeg + 64; ++k) {
                float2 w = *reinterpret_cast<const float2*>(ew2 + (size_t)k * UU + c0);
                #pragma unroll
                for (int r = 0; r < MROW; ++r) {
                    float hv = h1s[r * H2 + k];
                    acc[r].x += hv * w.x; acc[r].y += hv * w.y;
                }
            }
            #pragma unroll
            for (int r = 0; r < MROW; ++r) redf2[ks * 512 + r * 128 + cc] = acc[r];
        }
        __syncthreads();
        {
            int o = tid;
            float v = eb2[o & 255];
            #pragma unroll
            for (int ks = 0; ks < 8; ++ks) v += redf[ks * 1024 + o];
            hs[o] = v;
        }
        __syncthreads();
        {
            int cc = tid & 127, c0 = cc * 2;
            int ks = tid >> 7;
            int kbeg = ks * 32;
            float2 acc[MROW];
            #pragma unroll
            for (int r = 0; r < MROW; ++r) acc[r] = make_float2(0.f, 0.f);
            #pragma unroll 8
            for (int k = kbeg; k < kbeg + 32; ++k) {
                float2 w = *reinterpret_cast<const float2*>(uw + (size_t)k * UU + c0);
                #pragma unroll
                for (int r = 0; r < MROW; ++r) {
                    float hv = hs[r * UU + k];
                    acc[r].x += hv * w.x; acc[r].y += hv * w.y;
                }
            }
            #pragma unroll
            for (int r = 0; r < MROW; ++r) redf2[ks * 512 + r * 128 + cc] = acc[r];
        }
        __syncthreads();
        {
            int o = tid, r = o >> 8, c = o & 255;
            float v = ub[c];
            #pragma unroll
            for (int ks = 0; ks < 8; ++ks) v += redf[ks * 1024 + o];
            combs[r][c] = v;
        }
        __syncthreads();
        {
            int r = tid >> 8, c = tid & 255;
            float u = combs[r][c];
            float hb = hs[r * UU + c] * bww[c];
            float s0 = u, s1 = u * u, s2 = hb;
            #pragma unroll
            for (int mk = 1; mk < 64; mk <<= 1) {
                s0 += __shfl_xor(s0, mk);
                s1 += __shfl_xor(s1, mk);
                s2 += __shfl_xor(s2, mk);
            }
            if ((tid & 63) == 0) {
                int w = tid >> 6;
                wred[w][0] = s0; wred[w][1] = s1; wred[w][2] = s2;
            }
        }
        __syncthreads();
        if (tid < MROW) {
            int r = tid;
            float t0 = 0.f, t1 = 0.f, t2 = 0.f;
            #pragma unroll
            for (int w = 4 * r; w < 4 * r + 4; ++w) { t0 += wred[w][0]; t1 += wred[w][1]; t2 += wred[w][2]; }
            float mean = t0 * (1.0f / UU);
            float var = t1 * (1.0f / UU) - mean * mean;
            rowstat[r][0] = mean; rowstat[r][1] = rsqrtf(var + LN_EPS); rowstat[r][2] = t2;
        }
        __syncthreads();
        {
            int r = tid >> 8, c = tid & 255;
            float u = combs[r][c];
            combs[r][c] = (u - rowstat[r][0]) * rowstat[r][1] * g2v[c] + b2v[c];
            if (tid < MROW) combs[tid][UU] = rowstat[tid][2];
        }
        __syncthreads();
        {
            int cc = tid & 255, c0 = cc * 2;
            int ks = tid >> 8;
            int kbeg = ks * 64;
            int kend = (ks == 3) ? (UU + 1) : kbeg + 64;
            float2 acc[MROW];
            #pragma unroll
            for (int r = 0; r < MROW; ++r) acc[r] = make_float2(0.f, 0.f);
            #pragma unroll 8
            for (int k = kbeg; k < kend; ++k) {
                float2 w = *reinterpret_cast<const float2*>(dw1 + (size_t)k * H2 + c0);
                #pragma unroll
                for (int r = 0; r < MROW; ++r) {
                    float cv = combs[r][k];
                    acc[r].x += cv * w.x; acc[r].y += cv * w.y;
                }
            }
            #pragma unroll
            for (int r = 0; r < MROW; ++r) redf2[ks * 1024 + r * 256 + cc] = acc[r];
        }
        __syncthreads();
        {
            #pragma unroll
            for (int jj = 0; jj < 2; ++jj) {
                int o = tid + jj * 1024;
                float v = redf[o] + redf[2048 + o] + redf[4096 + o] + redf[6144 + o] + db1[o & 511];
                gs[o] = tanhf(v);
            }
        }
        __syncthreads();
        {
            int o = tid & 31, kc = tid >> 5;
            int r = o >> 3, f = o & 7;
            int kbeg = kc * 16;
            float p = 0.f;
            #pragma unroll 4
            for (int k = kbeg; k < kbeg + 16; ++k)
                p += gs[r * H2 + k] * dw2[(size_t)k * NOUT + f];
            red2[kc][o] = p;
        }
        __syncthreads();
        if (tid < 32) {
            int o = tid, r = o >> 3, f = o & 7;
            int b = b0 + r;
            float y = db2[f];
            #pragma unroll
            for (int kc = 0; kc < 32; ++kc) y += red2[kc][o];
            if (f == fx0) y = inputs[((size_t)b * S_LEN + i + 1) * FIN + 1 + fx0];
            if (f == fx1) y = inputs[((size_t)b * S_LEN + i + 1) * FIN + 1 + fx1];
            ynew[r][f] = y;
            out[((size_t)(f * 1024 + b)) * NSTEP + t] = y;
        }
        __syncthreads();
        {
            float wshift = 0.f;
            int sr = 0, sp = 0, sf = 0;
            bool doshift = tid < MROW * LBK * NOUT;
            if (doshift) {
                sr = tid / (LBK * NOUT);
                int rem = tid % (LBK * NOUT);
                sp = rem / NOUT; sf = rem % NOUT;
                wshift = (sp < LBK - 1) ? win[sr][sp + 1][sf] : ynew[sr][sf];
            }
            __syncthreads();
            if (doshift) win[sr][sp][sf] = wshift;
        }
        __syncthreads();
    }
}

extern "C" void kernel_launch(void* const* d_in, const int* in_sizes, int n_in,
                              void* d_out, int out_size, void* d_ws, size_t ws_size,
                              hipStream_t stream) {
    (void)in_sizes; (void)n_in; (void)out_size;
    const bool use_mfma = (d_ws != nullptr) && (ws_size >= (size_t)W_TOT * sizeof(unsigned short));
    if (use_mfma) {
        unsigned short* pool = (unsigned short*)d_ws;
        convw<<<(W_TOT + 255) / 256, 256, 0, stream>>>(
            (const float*)d_in[3], (const float*)d_in[5], (const float*)d_in[7],
            (const float*)d_in[12], (const float*)d_in[14], pool);
        solver<<<GRID, 1024, 0, stream>>>(
            (const float*)d_in[0], pool,
            (const float*)d_in[1], (const float*)d_in[2],
            (const float*)d_in[4], (const float*)d_in[6],
            (const float*)d_in[8], (const float*)d_in[9],
            (const float*)d_in[10], (const float*)d_in[11],
            (const float*)d_in[12], (const float*)d_in[13],
            (const float*)d_in[15], (const int*)d_in[16],
            (float*)d_out);
    } else {
        solver_fb<<<256, NTF, 0, stream>>>(
            (const float*)d_in[0],
            (const float*)d_in[1], (const float*)d_in[2],
            (const float*)d_in[3], (const float*)d_in[4],
            (const float*)d_in[5], (const float*)d_in[6],
            (const float*)d_in[7], (const float*)d_in[8],
            (const float*)d_in[9], (const float*)d_in[10],
            (const float*)d_in[11],
            (const float*)d_in[12], (const float*)d_in[13],
            (const float*)d_in[14], (const float*)d_in[15],
            (const int*)d_in[16],
            (float*)d_out);
    }
}

// Round 6
// 19563.098 us; speedup vs baseline: 2.4226x; 2.4226x over previous
//
#include <hip/hip_runtime.h>
#include <math.h>

#define S_LEN 2048
#define FIN 9
#define NOUT 8
#define LBK 3
#define DD 11
#define K1 33
#define H2 512
#define UU 256
#define NSTEP 2044
#define MR 8
#define GRID 128
#define LN_EPS 1e-3f

typedef __attribute__((ext_vector_type(8))) short short8;
typedef __attribute__((ext_vector_type(4))) float f32x4;
typedef __attribute__((ext_vector_type(4))) unsigned short us4;

// ---- packed B-fragment pool (bf16): tile (nt,kt): 64 lanes x 8 bf16,
// elem = B[k][n], k = kt*32 + (lane>>4)*8 + j, n = nt*16 + (lane&15)
#define F_EW1 (32 * 2 * 512)
#define F_EW2 (16 * 16 * 512)
#define F_UW  (16 * 8 * 512)
#define F_DW1 (32 * 8 * 512)
#define F_DW2 (1 * 16 * 512)
#define O_EW1 0
#define O_EW2 (O_EW1 + F_EW1)
#define O_UW  (O_EW2 + F_EW2)
#define O_DW1 (O_UW + F_UW)
#define O_DW2 (O_DW1 + F_DW1)
#define W_TOT (O_DW2 + F_DW2)   // 368640 elems = 737280 B

__device__ __forceinline__ unsigned short f2bf(float f) {
    unsigned u = __float_as_uint(f);
    u = (u + 0x7fffu + ((u >> 16) & 1u)) >> 16;
    return (unsigned short)u;
}
__device__ __forceinline__ float bf2f(unsigned short u) {
    return __uint_as_float(((unsigned)u) << 16);
}
__device__ __forceinline__ float ftanh(float x) {
    float ax = fabsf(x);
    float e = __expf(-2.0f * ax);
    float r = __fdividef(1.0f - e, 1.0f + e);
    return copysignf(r, x);
}

extern "C" __global__ void convw(const float* __restrict__ ew1, const float* __restrict__ ew2,
                                 const float* __restrict__ uw,  const float* __restrict__ dw1,
                                 const float* __restrict__ dw2, unsigned short* __restrict__ o)
{
    int i = blockIdx.x * blockDim.x + threadIdx.x;
    if (i >= W_TOT) return;
    int p, KT, K, N; const float* W;
    if (i < O_EW2)      { p = i - O_EW1; KT = 2;  K = 33;  N = 512; W = ew1; }
    else if (i < O_UW)  { p = i - O_EW2; KT = 16; K = 512; N = 256; W = ew2; }
    else if (i < O_DW1) { p = i - O_UW;  KT = 8;  K = 256; N = 256; W = uw;  }
    else if (i < O_DW2) { p = i - O_DW1; KT = 8;  K = 256; N = 512; W = dw1; }
    else                { p = i - O_DW2; KT = 16; K = 512; N = 8;   W = dw2; }
    int frag = p >> 9, rem = p & 511;
    int ln = rem >> 3, j = rem & 7;
    int nt = frag / KT, kt = frag % KT;
    int k = kt * 32 + (ln >> 4) * 8 + j;
    int n = nt * 16 + (ln & 15);
    float v = 0.f;
    if (k < K && n < N) v = W[k * N + n];
    o[i] = f2bf(v);
}

extern "C" __global__ void __launch_bounds__(1024, 4)
solver(const float* __restrict__ inputs,
       const unsigned short* __restrict__ pool,
       const float* __restrict__ g1v, const float* __restrict__ b1v,
       const float* __restrict__ eb1, const float* __restrict__ eb2,
       const float* __restrict__ ub,  const float* __restrict__ g2v,
       const float* __restrict__ b2v, const float* __restrict__ bww,
       const float* __restrict__ dw1, const float* __restrict__ db1,
       const float* __restrict__ db2, const int* __restrict__ fixv,
       float* __restrict__ out)
{
    __shared__ unsigned short xs[MR * 72];     // LN1 out (33 used, zeros to 64)
    __shared__ unsigned short h1[MR * 520];    // tanh(enc1)
    __shared__ unsigned short hsb[MR * 264];   // enc2 out
    __shared__ __align__(16) float uu[MR * 260];   // upd out fp32
    __shared__ unsigned short cmb[MR * 264];   // LN2 out bf16
    __shared__ unsigned short gsb[MR * 520];   // tanh(dec1)
    __shared__ float red2[16][MR][9];
    __shared__ float ects[MR];
    __shared__ float ring[3][MR][NOUT];
    __shared__ float s_eb1[512], s_eb2[256], s_ub[256], s_db1[512], s_db2[8];
    __shared__ __align__(16) float s_bw[256];
    __shared__ __align__(16) float s_g2[256];
    __shared__ __align__(16) float s_b2[256];
    __shared__ float s_w257[512];
    __shared__ float s_g1[DD], s_b1[DD];

    const int tid = threadIdx.x;
    const int lane = tid & 63;
    const int wv = tid >> 6;      // 0..15
    const int q = lane >> 4;      // 0..3
    const int lc = lane & 15;     // tile col / output col
    const int lr = lc & 7;        // A-row (rows 8..15 duplicate 0..7)
    const int b0 = blockIdx.x * MR;
    const int fx0 = fixv[0], fx1 = fixv[1];

    // ---- preamble: params, zero xs, ring init ----
    for (int z = tid; z < MR * 72; z += 1024) xs[z] = 0;
    for (int z = tid; z < 512; z += 1024) { s_eb1[z] = eb1[z]; s_db1[z] = db1[z]; s_w257[z] = dw1[256 * 512 + z]; }
    for (int z = tid; z < 256; z += 1024) { s_eb2[z] = eb2[z]; s_ub[z] = ub[z]; s_bw[z] = bww[z]; s_g2[z] = g2v[z]; s_b2[z] = b2v[z]; }
    if (tid < 8) s_db2[tid] = db2[tid];
    if (tid >= 16 && tid < 16 + DD) { s_g1[tid - 16] = g1v[tid - 16]; s_b1[tid - 16] = b1v[tid - 16]; }
    if (tid < MR * LBK * NOUT) {
        int r = tid / (LBK * NOUT);
        int rem = tid % (LBK * NOUT);
        int p = rem / NOUT, f = rem % NOUT;
        ring[p][r][f] = inputs[((size_t)(b0 + r) * S_LEN + p) * FIN + 1 + f];
    }

    // ---- pinned step-invariant fragments: uw (32 VGPR) + dw2 (4 VGPR) ----
    short8 fD[8], fG;
    #pragma unroll
    for (int kt = 0; kt < 8; ++kt)
        fD[kt] = *(const short8*)&pool[O_UW + (((wv << 3) + kt) << 9) + (lane << 3)];
    fG = *(const short8*)&pool[O_DW2 + (wv << 9) + (lane << 3)];

    __syncthreads();

    // ---- stage A for t=0 ----
    if (tid < MR * LBK) {
        int r = tid / LBK, p = tid % LBK;
        int b = b0 + r;
        int tt = p;
        float ld = inputs[((size_t)b * S_LEN + tt) * FIN];
        float df = (tt > 0) ? ld - inputs[((size_t)b * S_LEN + tt - 1) * FIN] : 0.f;
        float v[DD];
        v[0] = ld; v[1] = ld; v[2] = df;
        #pragma unroll
        for (int f = 0; f < NOUT; ++f) v[3 + f] = ring[tt % 3][r][f];
        float m = 0.f;
        #pragma unroll
        for (int j = 0; j < DD; ++j) m += v[j];
        m *= (1.0f / DD);
        float var = 0.f;
        #pragma unroll
        for (int j = 0; j < DD; ++j) { float d = v[j] - m; var += d * d; }
        var *= (1.0f / DD);
        float rs = rsqrtf(var + LN_EPS);
        #pragma unroll
        for (int j = 0; j < DD; ++j)
            xs[r * 72 + p * DD + j] = f2bf((v[j] - m) * rs * s_g1[j] + s_b1[j]);
    }
    __syncthreads();

    for (int t = 0; t < NSTEP; ++t) {
        // ==== stage B: h1 = tanh(x @ ew1 + eb1), 33(pad64)->512 ====
        {
            #pragma unroll
            for (int half = 0; half < 2; ++half) {
                int nt = 2 * wv + half;
                float bias = s_eb1[nt * 16 + lc];
                f32x4 acc = {bias, bias, bias, bias};
                #pragma unroll
                for (int kt = 0; kt < 2; ++kt) {
                    short8 af = *(const short8*)&xs[lr * 72 + kt * 32 + q * 8];
                    short8 bf = *(const short8*)&pool[O_EW1 + (((nt << 1) + kt) << 9) + (lane << 3)];
                    acc = __builtin_amdgcn_mfma_f32_16x16x32_bf16(af, bf, acc, 0, 0, 0);
                }
                if (q < 2) {
                    int col = nt * 16 + lc;
                    #pragma unroll
                    for (int r = 0; r < 4; ++r)
                        h1[(q * 4 + r) * 520 + col] = f2bf(ftanh(acc[r]));
                }
            }
        }
        __syncthreads();

        // ==== stage C: h = h1 @ ew2 + eb2, 512->256 ====
        {
            float bias = s_eb2[wv * 16 + lc];
            f32x4 acc = {bias, bias, bias, bias};
            #pragma unroll 4
            for (int kt = 0; kt < 16; ++kt) {
                short8 af = *(const short8*)&h1[lr * 520 + kt * 32 + q * 8];
                short8 bf = *(const short8*)&pool[O_EW2 + (((wv << 4) + kt) << 9) + (lane << 3)];
                acc = __builtin_amdgcn_mfma_f32_16x16x32_bf16(af, bf, acc, 0, 0, 0);
            }
            if (q < 2) {
                int col = wv * 16 + lc;
                #pragma unroll
                for (int r = 0; r < 4; ++r)
                    hsb[(q * 4 + r) * 264 + col] = f2bf(acc[r]);
            }
        }
        __syncthreads();

        // ==== stage D: u = h @ uw + ub (pinned fD, zero loads) ====
        {
            float bias = s_ub[wv * 16 + lc];
            f32x4 acc = {bias, bias, bias, bias};
            #pragma unroll
            for (int kt = 0; kt < 8; ++kt) {
                short8 af = *(const short8*)&hsb[lr * 264 + kt * 32 + q * 8];
                acc = __builtin_amdgcn_mfma_f32_16x16x32_bf16(af, fD[kt], acc, 0, 0, 0);
            }
            if (q < 2) {
                int col = wv * 16 + lc;
                #pragma unroll
                for (int r = 0; r < 4; ++r)
                    uu[(q * 4 + r) * 260 + col] = acc[r];
            }
        }
        __syncthreads();

        // ==== LN2 stats + cmb (waves 0..7, row = wv) ====
        if (wv < 8) {
            const int r = wv;
            float4 u4 = *(const float4*)&uu[r * 260 + lane * 4];
            us4 h4 = *(const us4*)&hsb[r * 264 + lane * 4];
            float4 bw4 = *(const float4*)&s_bw[lane * 4];
            float s0 = u4.x + u4.y + u4.z + u4.w;
            float s1 = u4.x * u4.x + u4.y * u4.y + u4.z * u4.z + u4.w * u4.w;
            float s2 = bf2f(h4[0]) * bw4.x + bf2f(h4[1]) * bw4.y + bf2f(h4[2]) * bw4.z + bf2f(h4[3]) * bw4.w;
            #pragma unroll
            for (int mk = 1; mk < 64; mk <<= 1) {
                s0 += __shfl_xor(s0, mk);
                s1 += __shfl_xor(s1, mk);
                s2 += __shfl_xor(s2, mk);
            }
            float mean = s0 * (1.0f / UU);
            float var = s1 * (1.0f / UU) - mean * mean;
            float rstd = rsqrtf(var + LN_EPS);
            if (lane == 0) ects[r] = s2;
            float4 g4 = *(const float4*)&s_g2[lane * 4];
            float4 bb4 = *(const float4*)&s_b2[lane * 4];
            us4 o;
            o[0] = f2bf((u4.x - mean) * rstd * g4.x + bb4.x);
            o[1] = f2bf((u4.y - mean) * rstd * g4.y + bb4.y);
            o[2] = f2bf((u4.z - mean) * rstd * g4.z + bb4.z);
            o[3] = f2bf((u4.w - mean) * rstd * g4.w + bb4.w);
            *(us4*)&cmb[r * 264 + lane * 4] = o;
        }
        __syncthreads();

        // ==== stage F: g = tanh(comb @ dw1 + ect*w257 + db1), then fused
        // ==== stage G: y-partials = g @ dw2 (pinned fG; same-wave gsb reuse) ====
        {
            #pragma unroll
            for (int half = 0; half < 2; ++half) {
                int nt = 2 * wv + half;
                float bias = s_db1[nt * 16 + lc];
                f32x4 acc = {bias, bias, bias, bias};
                #pragma unroll 4
                for (int kt = 0; kt < 8; ++kt) {
                    short8 af = *(const short8*)&cmb[lr * 264 + kt * 32 + q * 8];
                    short8 bf = *(const short8*)&pool[O_DW1 + ((((nt) << 3) + kt) << 9) + (lane << 3)];
                    acc = __builtin_amdgcn_mfma_f32_16x16x32_bf16(af, bf, acc, 0, 0, 0);
                }
                if (q < 2) {
                    int col = nt * 16 + lc;
                    float wc = s_w257[col];
                    #pragma unroll
                    for (int r = 0; r < 4; ++r) {
                        int row = q * 4 + r;
                        gsb[row * 520 + col] = f2bf(ftanh(acc[r] + ects[row] * wc));
                    }
                }
            }
            // G: wave wv handles kt=wv; gsb cols [32wv,32wv+32) were written by this wave
            f32x4 acc = {0.f, 0.f, 0.f, 0.f};
            {
                short8 af = *(const short8*)&gsb[lr * 520 + wv * 32 + q * 8];
                acc = __builtin_amdgcn_mfma_f32_16x16x32_bf16(af, fG, acc, 0, 0, 0);
            }
            if (q < 2 && lc < 8) {
                #pragma unroll
                for (int r = 0; r < 4; ++r)
                    red2[wv][q * 4 + r][lc] = acc[r];
            }
        }
        __syncthreads();

        // ==== finalize + stage A(t+1) (wave 0) ====
        if (wv == 0) {
            int r = lane >> 3, f = lane & 7;
            int b = b0 + r;
            float y = s_db2[f];
            #pragma unroll
            for (int w = 0; w < 16; ++w) y += red2[w][r][f];
            if (f == fx0) y = inputs[((size_t)b * S_LEN + t + 4) * FIN + 1 + fx0];
            if (f == fx1) y = inputs[((size_t)b * S_LEN + t + 4) * FIN + 1 + fx1];
            out[((size_t)(f * 1024 + b)) * NSTEP + t] = y;
            ring[t % 3][r][f] = y;
            // stage A for step t+1 (same wave: ring writes above ordered before these reads)
            if (lane < MR * LBK) {
                int ar = lane / LBK, p = lane % LBK;
                int ab = b0 + ar;
                int tt = t + 1 + p;
                float ld = inputs[((size_t)ab * S_LEN + tt) * FIN];
                float df = ld - inputs[((size_t)ab * S_LEN + tt - 1) * FIN];
                float v[DD];
                v[0] = ld; v[1] = ld; v[2] = df;
                #pragma unroll
                for (int ff = 0; ff < NOUT; ++ff) v[3 + ff] = ring[tt % 3][ar][ff];
                float m = 0.f;
                #pragma unroll
                for (int j = 0; j < DD; ++j) m += v[j];
                m *= (1.0f / DD);
                float var = 0.f;
                #pragma unroll
                for (int j = 0; j < DD; ++j) { float d = v[j] - m; var += d * d; }
                var *= (1.0f / DD);
                float rs = rsqrtf(var + LN_EPS);
                #pragma unroll
                for (int j = 0; j < DD; ++j)
                    xs[ar * 72 + p * DD + j] = f2bf((v[j] - m) * rs * s_g1[j] + s_b1[j]);
            }
        }
        __syncthreads();
    }
}

// ================= fallback (fp32 VALU, R3-proven) =================
#define MROW 4
#define NTF 1024
__global__ __launch_bounds__(NTF)
void solver_fb(const float* __restrict__ inputs,
               const float* __restrict__ g1v, const float* __restrict__ b1v,
               const float* __restrict__ ew1, const float* __restrict__ eb1,
               const float* __restrict__ ew2, const float* __restrict__ eb2,
               const float* __restrict__ uw,  const float* __restrict__ ub,
               const float* __restrict__ g2v, const float* __restrict__ b2v,
               const float* __restrict__ bww,
               const float* __restrict__ dw1, const float* __restrict__ db1,
               const float* __restrict__ dw2, const float* __restrict__ db2,
               const int* __restrict__ fixv,
               float* __restrict__ out)
{
    __shared__ float x33[MROW][K1];
    __shared__ float h1s[MROW * H2];
    __shared__ float hs[MROW * UU];
    __shared__ float combs[MROW][UU + 1];
    __shared__ float gs[MROW * H2];
    __shared__ float win[MROW][LBK][NOUT];
    __shared__ float redf[8192];
    __shared__ float red2[32][32];
    __shared__ float wred[16][3];
    __shared__ float rowstat[MROW][3];
    __shared__ float ynew[MROW][NOUT];
    float2* redf2 = reinterpret_cast<float2*>(redf);
    const int tid = threadIdx.x;
    const int b0 = blockIdx.x * MROW;
    const int fx0 = fixv[0], fx1 = fixv[1];
    if (tid < MROW * LBK * NOUT) {
        int r = tid / (LBK * NOUT);
        int rem = tid % (LBK * NOUT);
        int p = rem / NOUT, f = rem % NOUT;
        win[r][p][f] = inputs[((size_t)(b0 + r) * S_LEN + p) * FIN + 1 + f];
    }
    __syncthreads();
    for (int t = 0; t < NSTEP; ++t) {
        const int i = t + LBK;
        if (tid < MROW * LBK) {
            int r = tid / LBK, p = tid % LBK;
            int b = b0 + r;
            int tt = i - LBK + p;
            float ld = inputs[((size_t)b * S_LEN + tt) * FIN];
            float df = (tt > 0) ? ld - inputs[((size_t)b * S_LEN + tt - 1) * FIN] : 0.f;
            float v[DD];
            v[0] = ld; v[1] = ld; v[2] = df;
            #pragma unroll
            for (int f = 0; f < NOUT; ++f) v[3 + f] = win[r][p][f];
            float m = 0.f;
            #pragma unroll
            for (int j = 0; j < DD; ++j) m += v[j];
            m *= (1.0f / DD);
            float var = 0.f;
            #pragma unroll
            for (int j = 0; j < DD; ++j) { float d = v[j] - m; var += d * d; }
            var *= (1.0f / DD);
            float rs = rsqrtf(var + LN_EPS);
            #pragma unroll
            for (int j = 0; j < DD; ++j)
                x33[r][p * DD + j] = (v[j] - m) * rs * g1v[j] + b1v[j];
        }
        __syncthreads();
        {
            int cc = tid & 255, c0 = cc * 2;
            int ks = tid >> 8;
            int kbeg = ks * 8;
            int kend = (ks == 3) ? K1 : kbeg + 8;
            float2 acc[MROW];
            #pragma unroll
            for (int r = 0; r < MROW; ++r) acc[r] = make_float2(0.f, 0.f);
            for (int k = kbeg; k < kend; ++k) {
                float2 w = *reinterpret_cast<const float2*>(ew1 + (size_t)k * H2 + c0);
                #pragma unroll
                for (int r = 0; r < MROW; ++r) {
                    float xv = x33[r][k];
                    acc[r].x += xv * w.x; acc[r].y += xv * w.y;
                }
            }
            #pragma unroll
            for (int r = 0; r < MROW; ++r) redf2[ks * 1024 + r * 256 + cc] = acc[r];
        }
        __syncthreads();
        {
            #pragma unroll
            for (int jj = 0; jj < 2; ++jj) {
                int o = tid + jj * 1024;
                float v = redf[o] + redf[2048 + o] + redf[4096 + o] + redf[6144 + o] + eb1[o & 511];
                h1s[o] = tanhf(v);
            }
        }
        __syncthreads();
        {
            int cc = tid & 127, c0 = cc * 2;
            int ks = tid >> 7;
            int kbeg = ks * 64;
            float2 acc[MROW];
            #pragma unroll
            for (int r = 0; r < MROW; ++r) acc[r] = make_float2(0.f, 0.f);
            #pragma unroll 8
            for (int k = kbeg; k < kbeg + 64; ++k) {
                float2 w = *reinterpret_cast<const float2*>(ew2 + (size_t)k * UU + c0);
                #pragma unroll
                for (int r = 0; r < MROW; ++r) {
                    float hv = h1s[r * H2 + k];
                    acc[r].x += hv * w.x; acc[r].y += hv * w.y;
                }
            }
            #pragma unroll
            for (int r = 0; r < MROW; ++r) redf2[ks * 512 + r * 128 + cc] = acc[r];
        }
        __syncthreads();
        {
            int o = tid;
            float v = eb2[o & 255];
            #pragma unroll
            for (int ks = 0; ks < 8; ++ks) v += redf[ks * 1024 + o];
            hs[o] = v;
        }
        __syncthreads();
        {
            int cc = tid & 127, c0 = cc * 2;
            int ks = tid >> 7;
            int kbeg = ks * 32;
            float2 acc[MROW];
            #pragma unroll
            for (int r = 0; r < MROW; ++r) acc[r] = make_float2(0.f, 0.f);
            #pragma unroll 8
            for (int k = kbeg; k < kbeg + 32; ++k) {
                float2 w = *reinterpret_cast<const float2*>(uw + (size_t)k * UU + c0);
                #pragma unroll
                for (int r = 0; r < MROW; ++r) {
                    float hv = hs[r * UU + k];
                    acc[r].x += hv * w.x; acc[r].y += hv * w.y;
                }
            }
            #pragma unroll
            for (int r = 0; r < MROW; ++r) redf2[ks * 512 + r * 128 + cc] = acc[r];
        }
        __syncthreads();
        {
            int o = tid, r = o >> 8, c = o & 255;
            float v = ub[c];
            #pragma unroll
            for (int ks = 0; ks < 8; ++ks) v += redf[ks * 1024 + o];
            combs[r][c] = v;
        }
        __syncthreads();
        {
            int r = tid >> 8, c = tid & 255;
            float u = combs[r][c];
            float hb = hs[r * UU + c] * bww[c];
            float s0 = u, s1 = u * u, s2 = hb;
            #pragma unroll
            for (int mk = 1; mk < 64; mk <<= 1) {
                s0 += __shfl_xor(s0, mk);
                s1 += __shfl_xor(s1, mk);
                s2 += __shfl_xor(s2, mk);
            }
            if ((tid & 63) == 0) {
                int w = tid >> 6;
                wred[w][0] = s0; wred[w][1] = s1; wred[w][2] = s2;
            }
        }
        __syncthreads();
        if (tid < MROW) {
            int r = tid;
            float t0 = 0.f, t1 = 0.f, t2 = 0.f;
            #pragma unroll
            for (int w = 4 * r; w < 4 * r + 4; ++w) { t0 += wred[w][0]; t1 += wred[w][1]; t2 += wred[w][2]; }
            float mean = t0 * (1.0f / UU);
            float var = t1 * (1.0f / UU) - mean * mean;
            rowstat[r][0] = mean; rowstat[r][1] = rsqrtf(var + LN_EPS); rowstat[r][2] = t2;
        }
        __syncthreads();
        {
            int r = tid >> 8, c = tid & 255;
            float u = combs[r][c];
            combs[r][c] = (u - rowstat[r][0]) * rowstat[r][1] * g2v[c] + b2v[c];
            if (tid < MROW) combs[tid][UU] = rowstat[tid][2];
        }
        __syncthreads();
        {
            int cc = tid & 255, c0 = cc * 2;
            int ks = tid >> 8;
            int kbeg = ks * 64;
            int kend = (ks == 3) ? (UU + 1) : kbeg + 64;
            float2 acc[MROW];
            #pragma unroll
            for (int r = 0; r < MROW; ++r) acc[r] = make_float2(0.f, 0.f);
            #pragma unroll 8
            for (int k = kbeg; k < kend; ++k) {
                float2 w = *reinterpret_cast<const float2*>(dw1 + (size_t)k * H2 + c0);
                #pragma unroll
                for (int r = 0; r < MROW; ++r) {
                    float cv = combs[r][k];
                    acc[r].x += cv * w.x; acc[r].y += cv * w.y;
                }
            }
            #pragma unroll
            for (int r = 0; r < MROW; ++r) redf2[ks * 1024 + r * 256 + cc] = acc[r];
        }
        __syncthreads();
        {
            #pragma unroll
            for (int jj = 0; jj < 2; ++jj) {
                int o = tid + jj * 1024;
                float v = redf[o] + redf[2048 + o] + redf[4096 + o] + redf[6144 + o] + db1[o & 511];
                gs[o] = tanhf(v);
            }
        }
        __syncthreads();
        {
            int o = tid & 31, kc = tid >> 5;
            int r = o >> 3, f = o & 7;
            int kbeg = kc * 16;
            float p = 0.f;
            #pragma unroll 4
            for (int k = kbeg; k < kbeg + 16; ++k)
                p += gs[r * H2 + k] * dw2[(size_t)k * NOUT + f];
            red2[kc][o] = p;
        }
        __syncthreads();
        if (tid < 32) {
            int o = tid, r = o >> 3, f = o & 7;
            int b = b0 + r;
            float y = db2[f];
            #pragma unroll
            for (int kc = 0; kc < 32; ++kc) y += red2[kc][o];
            if (f == fx0) y = inputs[((size_t)b * S_LEN + i + 1) * FIN + 1 + fx0];
            if (f == fx1) y = inputs[((size_t)b * S_LEN + i + 1) * FIN + 1 + fx1];
            ynew[r][f] = y;
            out[((size_t)(f * 1024 + b)) * NSTEP + t] = y;
        }
        __syncthreads();
        {
            float wshift = 0.f;
            int sr = 0, sp = 0, sf = 0;
            bool doshift = tid < MROW * LBK * NOUT;
            if (doshift) {
                sr = tid / (LBK * NOUT);
                int rem = tid % (LBK * NOUT);
                sp = rem / NOUT; sf = rem % NOUT;
                wshift = (sp < LBK - 1) ? win[sr][sp + 1][sf] : ynew[sr][sf];
            }
            __syncthreads();
            if (doshift) win[sr][sp][sf] = wshift;
        }
        __syncthreads();
    }
}

extern "C" void kernel_launch(void* const* d_in, const int* in_sizes, int n_in,
                              void* d_out, int out_size, void* d_ws, size_t ws_size,
                              hipStream_t stream) {
    (void)in_sizes; (void)n_in; (void)out_size;
    const bool use_mfma = (d_ws != nullptr) && (ws_size >= (size_t)W_TOT * sizeof(unsigned short));
    if (use_mfma) {
        unsigned short* pool = (unsigned short*)d_ws;
        convw<<<(W_TOT + 255) / 256, 256, 0, stream>>>(
            (const float*)d_in[3], (const float*)d_in[5], (const float*)d_in[7],
            (const float*)d_in[12], (const float*)d_in[14], pool);
        solver<<<GRID, 1024, 0, stream>>>(
            (const float*)d_in[0], pool,
            (const float*)d_in[1], (const float*)d_in[2],
            (const float*)d_in[4], (const float*)d_in[6],
            (const float*)d_in[8], (const float*)d_in[9],
            (const float*)d_in[10], (const float*)d_in[11],
            (const float*)d_in[12], (const float*)d_in[13],
            (const float*)d_in[15], (const int*)d_in[16],
            (float*)d_out);
    } else {
        solver_fb<<<256, NTF, 0, stream>>>(
            (const float*)d_in[0],
            (const float*)d_in[1], (const float*)d_in[2],
            (const float*)d_in[3], (const float*)d_in[4],
            (const float*)d_in[5], (const float*)d_in[6],
            (const float*)d_in[7], (const float*)d_in[8],
            (const float*)d_in[9], (const float*)d_in[10],
            (const float*)d_in[11],
            (const float*)d_in[12], (const float*)d_in[13],
            (const float*)d_in[14], (const float*)d_in[15],
            (const int*)d_in[16],
            (float*)d_out);
    }
}